// Round 18
// baseline (134.600 us; speedup 1.0000x reference)
//
#include <hip/hip_runtime.h>
#include <hip/hip_fp16.h>

#define Nn 512
#define NNe 262144
#define CST 546   // padded FFT-scratch stride (>= pidx(511)+1 = 546)

__device__ __forceinline__ float2 f2(float x, float y){ return make_float2(x, y); }
__device__ __forceinline__ float2 cadd(float2 a, float2 b){ return f2(a.x+b.x, a.y+b.y); }
__device__ __forceinline__ float2 csub(float2 a, float2 b){ return f2(a.x-b.x, a.y-b.y); }
__device__ __forceinline__ float2 cmul(float2 a, float2 b){
    return f2(a.x*b.x - a.y*b.y, a.x*b.y + a.y*b.x);
}
// LDS padding: spreads banks across all three radix-8 stage access patterns
__device__ __forceinline__ int pidx(int p){ return p + (p>>4) + (p>>7); }
// intra-wave fence: LDS ops of one wave execute in program order (validated R2)
#define WFENCE() __builtin_amdgcn_wave_barrier()

// 8-point DFT (symmetric matrix). SGN=-1: forward, SGN=+1: inverse kernel (no 1/N)
template<int SGN>
__device__ __forceinline__ void fft8(float2 a[8]){
    const float r = 0.7071067811865476f;
    const float S = (float)SGN;
    float2 u0 = cadd(a[0], a[4]), u1 = cadd(a[1], a[5]);
    float2 u2 = cadd(a[2], a[6]), u3 = cadd(a[3], a[7]);
    float2 v0 = csub(a[0], a[4]), v1 = csub(a[1], a[5]);
    float2 v2 = csub(a[2], a[6]), v3 = csub(a[3], a[7]);
    v1 = cmul(v1, f2(r, S*r));
    v2 = cmul(v2, f2(0.f, S));
    v3 = cmul(v3, f2(-r, S*r));
    float2 p0 = cadd(u0, u2), p1 = cadd(u1, u3);
    float2 q0 = csub(u0, u2), q1 = cmul(csub(u1, u3), f2(0.f, S));
    a[0] = cadd(p0, p1); a[4] = csub(p0, p1);
    a[2] = cadd(q0, q1); a[6] = csub(q0, q1);
    p0 = cadd(v0, v2); p1 = cadd(v1, v3);
    q0 = csub(v0, v2); q1 = cmul(csub(v1, v3), f2(0.f, S));
    a[1] = cadd(p0, p1); a[5] = csub(p0, p1);
    a[3] = cadd(q0, q1); a[7] = csub(q0, q1);
}

__device__ __forceinline__ float2 twdp(int idx, float inv){
    float ang = 6.283185307179586f * (inv * (float)idx);
    float s, c;
    __sincosf(ang, &s, &c);
    return f2(c, s);
}

// DIF radix-8^3, inline chain twiddles, pidx-padded scratch.
// In: v[q] = x[lane+64q] (natural). Out (REGS): v[k2] = X[64k2+8(lane&7)+(lane>>3)].
template<int SGN>
__device__ void fft512_dif_i(float2 v[8], float2* buf, int lane){
    fft8<SGN>(v);
    {
        float2 w1 = twdp(lane, 1.f/512.f);
        if (SGN < 0) w1.y = -w1.y;
        float2 w  = f2(1.f, 0.f);
        #pragma unroll
        for (int r = 0; r < 8; ++r){
            buf[pidx(r*64 + lane)] = cmul(v[r], w);
            w = cmul(w, w1);
        }
    }
    WFENCE();
    int rb = (lane >> 3) * 64, t2 = lane & 7;
    float2 y[8];
    #pragma unroll
    for (int q = 0; q < 8; ++q) y[q] = buf[pidx(rb + t2 + 8*q)];
    fft8<SGN>(y);
    WFENCE();
    {
        float2 w2 = twdp(t2, 1.f/64.f);
        if (SGN < 0) w2.y = -w2.y;
        float2 w  = f2(1.f, 0.f);
        #pragma unroll
        for (int r = 0; r < 8; ++r){
            buf[pidx(rb + r*8 + t2)] = cmul(y[r], w);
            w = cmul(w, w2);
        }
    }
    WFENCE();
    int base = rb + t2*8;
    #pragma unroll
    for (int q = 0; q < 8; ++q) v[q] = buf[pidx(base + q)];
    fft8<SGN>(v);
}

// DIT (transposed DIF), inline chains, pidx scratch. In (REGS): tau slots. Out: natural.
template<int SGN>
__device__ void fft512_dit_i(float2 v[8], float2* buf, int lane){
    int rb = (lane >> 3) * 64, t2 = lane & 7;
    fft8<SGN>(v);
    int base = rb + t2*8;
    #pragma unroll
    for (int q = 0; q < 8; ++q) buf[pidx(base + q)] = v[q];
    WFENCE();
    float2 y[8];
    #pragma unroll
    for (int r = 0; r < 8; ++r) y[r] = buf[pidx(rb + r*8 + t2)];
    {
        float2 w2 = twdp(t2, 1.f/64.f);
        if (SGN < 0) w2.y = -w2.y;
        float2 w  = f2(1.f, 0.f);
        #pragma unroll
        for (int r = 0; r < 8; ++r){
            y[r] = cmul(y[r], w);
            w = cmul(w, w2);
        }
    }
    fft8<SGN>(y);
    WFENCE();
    #pragma unroll
    for (int q = 0; q < 8; ++q) buf[pidx(rb + t2 + 8*q)] = y[q];
    WFENCE();
    #pragma unroll
    for (int r = 0; r < 8; ++r) v[r] = buf[pidx(r*64 + lane)];
    {
        float2 w1 = twdp(lane, 1.f/512.f);
        if (SGN < 0) w1.y = -w1.y;
        float2 w  = f2(1.f, 0.f);
        #pragma unroll
        for (int r = 0; r < 8; ++r){
            v[r] = cmul(v[r], w);
            w = cmul(w, w1);
        }
    }
    fft8<SGN>(v);
}

// K1: temp[kj] = row-IFFT( x_hat * psi_hat[kj] ), fp16 tau slots, row-major;
// also emits psi2 = |psi|^2 fp16 (natural order).
__global__ __launch_bounds__(256, 6)
void k_mulrow(const float2* __restrict__ xh, const float* __restrict__ pr,
              const float* __restrict__ pi, __half2* __restrict__ temp,
              __half* __restrict__ psi2h){
    __shared__ float2 lds[4][548];
    int wave = threadIdx.x >> 6, lane = threadIdx.x & 63;
    int img  = blockIdx.x >> 7;
    int row  = ((blockIdx.x & 127) << 2) | wave;
    size_t boff = (size_t)img * NNe + (size_t)row * Nn;
    const float2* xr = xh + (size_t)row * Nn;
    float2 v[8];
    #pragma unroll
    for (int q = 0; q < 8; ++q){
        int x = lane + 64*q;
        float2 xv = xr[x];
        float2 pv = f2(pr[boff + x], pi[boff + x]);
        psi2h[boff + x] = __float2half_rn(pv.x*pv.x + pv.y*pv.y);
        v[q] = cmul(xv, pv);
    }
    fft512_dif_i<1>(v, lds[wave], lane);
    __half2* outp = temp + boff;
    #pragma unroll
    for (int q = 0; q < 8; ++q) outp[64*q + lane] = __floats2half2_rn(v[q].x, v[q].y);
}

// K2 (fused, R12-proven best): col-IFFT + modulus + packed-real col-FFT.
// 16-column tiles (full 64-B read sectors); 8 waves, 2 cols/wave via Hermitian pack.
__global__ __launch_bounds__(512, 2)
void k_colfused(__half2* __restrict__ temp){
    __shared__ __half2 st[16][521];
    __shared__ float2 fbuf[8][CST];
    int img = blockIdx.x >> 5;
    int x0  = (blockIdx.x & 31) << 4;
    __half2* src = temp + (size_t)img * NNe + x0;
    for (int i = threadIdx.x; i < 2048; i += 512){
        int row = i >> 2, c4 = (i & 3) << 2;
        uint4 u = *(const uint4*)&src[(size_t)row * Nn + c4];
        st[c4+0][row] = *(__half2*)&u.x;
        st[c4+1][row] = *(__half2*)&u.y;
        st[c4+2][row] = *(__half2*)&u.z;
        st[c4+3][row] = *(__half2*)&u.w;
    }
    __syncthreads();
    int wave = threadIdx.x >> 6, lane = threadIdx.x & 63;
    const float sc = 3.814697265625e-06f;   // 1/NN (ifft2 normalization)
    float2* buf = fbuf[wave];
    int c0 = 2*wave, c1 = c0 + 1;
    float2 a[8], b[8];
    #pragma unroll
    for (int q = 0; q < 8; ++q) a[q] = __half22float2(st[c0][lane + 64*q]);
    fft512_dif_i<1>(a, buf, lane);          // col IFFT c0 -> tau regs
    WFENCE();
    #pragma unroll
    for (int q = 0; q < 8; ++q) b[q] = __half22float2(st[c1][lane + 64*q]);
    fft512_dif_i<1>(b, buf, lane);          // col IFFT c1 -> tau regs
    // modulus (pointwise, order-free) and pack: z = m0 + i*m1
    float2 z[8];
    #pragma unroll
    for (int q = 0; q < 8; ++q){
        float r0 = a[q].x*sc, i0 = a[q].y*sc;
        float r1 = b[q].x*sc, i1 = b[q].y*sc;
        z[q] = f2(sqrtf(r0*r0 + i0*i0 + 1e-8f), sqrtf(r1*r1 + i1*i1 + 1e-8f));
    }
    WFENCE();
    fft512_dit_i<-1>(z, buf, lane);         // one FFT for two real columns
    // Hermitian unpack: M0=(Z[k]+conj(Z[-k]))/2, M1=-i(Z[k]-conj(Z[-k]))/2
    #pragma unroll
    for (int q = 0; q < 8; ++q) buf[pidx(lane + 64*q)] = z[q];
    WFENCE();
    #pragma unroll
    for (int q = 0; q < 8; ++q){
        int k = lane + 64*q;
        float2 zr = buf[pidx((512 - k) & 511)];
        float2 zv = z[q];
        st[c0][k] = __floats2half2_rn(0.5f*(zv.x + zr.x), 0.5f*(zv.y - zr.y));
        st[c1][k] = __floats2half2_rn(0.5f*(zv.y + zr.y), 0.5f*(zr.x - zv.x));
    }
    __syncthreads();
    for (int i = threadIdx.x; i < 2048; i += 512){
        int row = i >> 2, c4 = (i & 3) << 2;
        uint4 u;
        *(__half2*)&u.x = st[c4+0][row];
        *(__half2*)&u.y = st[c4+1][row];
        *(__half2*)&u.z = st[c4+2][row];
        *(__half2*)&u.w = st[c4+3][row];
        *(uint4*)&src[(size_t)row * Nn + c4] = u;
    }
}

// K3: row FFT + |.|^2 -> power fp16 (scaled 2^-8).
__global__ __launch_bounds__(256, 6)
void k_rowpow(const __half2* __restrict__ temp, __half* __restrict__ powerh){
    __shared__ float2 lds[4][548];
    int wave = threadIdx.x >> 6, lane = threadIdx.x & 63;
    int img  = blockIdx.x >> 7;
    int row  = ((blockIdx.x & 127) << 2) | wave;
    const __half2* src = temp + (size_t)img * NNe + (size_t)row * Nn;
    float2 v[8];
    #pragma unroll
    for (int q = 0; q < 8; ++q) v[q] = __half22float2(src[64*q + lane]);
    fft512_dit_i<-1>(v, lds[wave], lane);
    __half* dst = powerh + (size_t)img * NNe + (size_t)row * Nn;
    #pragma unroll
    for (int q = 0; q < 8; ++q)
        dst[lane + 64*q] = __float2half_rn((v[q].x*v[q].x + v[q].y*v[q].y) * 0.00390625f);
}

// K5: C[48][49] = power[48][NN] x {psi2, phi2}[NN][49]. One block (4 waves) per
// 512-n slice (8 steps of 64); BLOCK-SHARED tiles; wave w owns output cols
// [13w, 13w+13). acc[6][2] regs. Also accumulates s0 partial (wave 0).
__global__ __launch_bounds__(256, 5)
void k_gemm(const __half* __restrict__ powerh, const __half* __restrict__ psi2h,
            const float* __restrict__ phr, const float* __restrict__ phii,
            const float2* __restrict__ xh, float* __restrict__ partC,
            float* __restrict__ partS0){
    __shared__ __align__(16) float P[48][68];
    __shared__ __align__(16) float W[56][68];
    int tid = threadIdx.x;
    int wave = tid >> 6, lane = tid & 63;
    int lm = lane >> 3, lw = lane & 7;
    float acc[6][2] = {};
    float s0acc = 0.f;
    // zero W pad rows once (rows 49..55)
    if (tid < 224){
        int r = 49 + (tid >> 5), c = (tid & 31);
        W[r][c] = 0.f; W[r][32 + c] = 0.f;
        if (c < 4) W[r][64 + c] = 0.f;
    }
    int n0 = blockIdx.x * 512;
    for (int st = 0; st < 8; ++st){
        int nb = n0 + st*64;
        __syncthreads();
        #pragma unroll
        for (int rr = 0; rr < 3; ++rr){
            int row = rr*16 + (tid >> 4);
            int c4  = (tid & 15) * 4;
            size_t off = (size_t)row*NNe + nb + c4;
            const __half2* p2 = (const __half2*)&powerh[off];
            float2 f0 = __half22float2(p2[0]);
            float2 f1 = __half22float2(p2[1]);
            *(float4*)&P[row][c4] = make_float4(f0.x, f0.y, f1.x, f1.y);
        }
        #pragma unroll
        for (int rr = 0; rr < 3; ++rr){
            int row = rr*16 + (tid >> 4);
            int c4  = (tid & 15) * 4;
            size_t off = (size_t)row*NNe + nb + c4;
            const __half2* p2 = (const __half2*)&psi2h[off];
            float2 f0 = __half22float2(p2[0]);
            float2 f1 = __half22float2(p2[1]);
            *(float4*)&W[row][c4] = make_float4(f0.x, f0.y, f1.x, f1.y);
        }
        if (tid < 16){
            int c4 = tid * 4;
            float4 a = *(const float4*)&phr[nb + c4];
            float4 b = *(const float4*)&phii[nb + c4];
            float4 w4;
            w4.x = a.x*a.x + b.x*b.x; w4.y = a.y*a.y + b.y*b.y;
            w4.z = a.z*a.z + b.z*b.z; w4.w = a.w*a.w + b.w*b.w;
            *(float4*)&W[48][c4] = w4;
        }
        __syncthreads();
        if (wave == 0){  // s0 partial: |x_hat[nb+lane]|^2 * phi2[nb+lane]
            float2 xv = xh[nb + lane];
            s0acc = fmaf(xv.x*xv.x + xv.y*xv.y, W[48][lane], s0acc);
        }
        int cb = wave * 13;      // this wave's column base
        #pragma unroll 2
        for (int nn = 0; nn < 64; nn += 4){
            float4 pa[6], wb[2];
            #pragma unroll
            for (int i = 0; i < 6; ++i) pa[i] = *(const float4*)&P[lm + 8*i][nn];
            #pragma unroll
            for (int j = 0; j < 2; ++j) wb[j] = *(const float4*)&W[cb + lw + 8*j][nn];
            #pragma unroll
            for (int i = 0; i < 6; ++i)
                #pragma unroll
                for (int j = 0; j < 2; ++j){
                    float s = acc[i][j];
                    s = fmaf(pa[i].x, wb[j].x, s);
                    s = fmaf(pa[i].y, wb[j].y, s);
                    s = fmaf(pa[i].z, wb[j].z, s);
                    s = fmaf(pa[i].w, wb[j].w, s);
                    acc[i][j] = s;
                }
        }
    }
    if (wave == 0){
        #pragma unroll
        for (int o = 32; o > 0; o >>= 1) s0acc += __shfl_down(s0acc, o, 64);
        if (lane == 0) partS0[blockIdx.x] = s0acc;
    }
    float* outp = partC + (size_t)blockIdx.x * 2400;
    int cb = wave * 13;
    #pragma unroll
    for (int i = 0; i < 6; ++i)
        #pragma unroll
        for (int j = 0; j < 2; ++j){
            int cr = lw + 8*j;           // 0..15, valid < 13
            int wc = cb + cr;
            int m  = lm + 8*i;
            if (cr < 13 && wc < 49) outp[m*50 + wc] = acc[i][j];
        }
}

// reduce 512 partial C slices -> 16 slices
__global__ __launch_bounds__(256)
void k_redc1(const float* __restrict__ partC, float* __restrict__ partC2){
    __shared__ float red[4][64];
    int es = threadIdx.x & 63, wave = threadIdx.x >> 6;
    int e = blockIdx.x*64 + es;
    int b0 = blockIdx.y*32 + wave*8;
    float s = 0.f;
    if (e < 2400){
        #pragma unroll
        for (int u = 0; u < 8; ++u) s += partC[(size_t)(b0+u)*2400 + e];
    }
    red[wave][es] = s;
    __syncthreads();
    if (wave == 0 && e < 2400)
        partC2[(size_t)blockIdx.y*2400 + e] = red[0][es]+red[1][es]+red[2][es]+red[3][es];
}

// final: fold 16 slices -> CF (LDS), s0 (512 partials), assemble 1009-elem output
__global__ __launch_bounds__(256)
void k_final(const float* __restrict__ partC2, const float* __restrict__ partS0,
             float* __restrict__ outp, float SC0, float SCC){
    __shared__ float CFs[2400];
    __shared__ float ssum[4];
    int tid = threadIdx.x, wave = tid >> 6, lane = tid & 63;
    for (int e = tid; e < 2400; e += 256){
        float s = 0.f;
        #pragma unroll
        for (int u = 0; u < 16; ++u) s += partC2[(size_t)u*2400 + e];
        CFs[e] = SCC * s;
    }
    float a = partS0[tid] + partS0[tid + 256];
    #pragma unroll
    for (int o = 32; o > 0; o >>= 1) a += __shfl_down(a, o, 64);
    if (lane == 0) ssum[wave] = a;
    __syncthreads();
    if (tid == 0) outp[0] = SC0 * (ssum[0]+ssum[1]+ssum[2]+ssum[3]);
    int off = 1;
    for (int i = 0; i < 6; ++i){
        if (tid < 8) outp[off + tid] = CFs[(tid*6 + i)*50 + 48];   // a[:, i]
        off += 8;
        if (i < 5){
            int nj = 5 - i, cnt = 64 * nj;
            for (int p = tid; p < cnt; p += 256){
                int j2 = p % nj;
                int km = p / nj;
                int m = km & 7, k = km >> 3;
                outp[off + p] = CFs[(k*6 + i)*50 + m*6 + (i + 1 + j2)];
            }
            off += cnt;
        }
    }
}

extern "C" void kernel_launch(void* const* d_in, const int* in_sizes, int n_in,
                              void* d_out, int out_size, void* d_ws, size_t ws_size,
                              hipStream_t stream){
    (void)in_sizes; (void)n_in; (void)out_size; (void)ws_size;
    const float2* xh  = (const float2*)d_in[0];
    const float*  phr = (const float*)d_in[1];
    const float*  phi_= (const float*)d_in[2];
    const float*  psr = (const float*)d_in[3];
    const float*  psi_= (const float*)d_in[4];
    float* outp = (float*)d_out;
    float* ws   = (float*)d_ws;

    // ws layout (f32 units): power(half)[24NN] | partC[512*2400] | partC2[16*2400] |
    //                        s0[512] | temp(half2)[48NN] | psi2(half)[24NN]
    size_t o_power = 0;
    size_t o_partC = o_power + (size_t)24 * NNe;
    size_t o_pC2   = o_partC + (size_t)512 * 2400;
    size_t o_s0    = o_pC2 + (size_t)16 * 2400;
    size_t o_temp  = o_s0 + 512;
    size_t o_psi2  = o_temp + (size_t)48 * NNe;
    __half*  powerh= (__half*)(ws + o_power);
    float*   partC = ws + o_partC;
    float*   partC2= ws + o_pC2;
    float*   ps0   = ws + o_s0;
    __half2* temp  = (__half2*)(ws + o_temp);
    __half*  psi2h = (__half*)(ws + o_psi2);

    const double INVd = 1.0 / (4.0 * 3.14159265358979323846 * 3.14159265358979323846);
    const float SC0 = (float)(INVd / (double)NNe);          // INV / NN (s0 path)
    const float SCC = (float)(INVd / (double)NNe * 256.0);  // + 2^8 power descale

    k_mulrow<<<dim3(48*128), dim3(256), 0, stream>>>(xh, psr, psi_, temp, psi2h);
    k_colfused<<<dim3(48*32), dim3(512), 0, stream>>>(temp);
    k_rowpow<<<dim3(48*128), dim3(256), 0, stream>>>(temp, powerh);
    k_gemm<<<dim3(512), dim3(256), 0, stream>>>(powerh, psi2h, phr, phi_, xh, partC, ps0);
    k_redc1<<<dim3(38, 16), dim3(256), 0, stream>>>(partC, partC2);
    k_final<<<dim3(1), dim3(256), 0, stream>>>(partC2, ps0, outp, SC0, SCC);
}

// Round 19
// 129.801 us; speedup vs baseline: 1.0370x; 1.0370x over previous
//
#include <hip/hip_runtime.h>
#include <hip/hip_fp16.h>

#define Nn 512
#define NNe 262144
#define CST 546   // padded FFT-scratch stride (>= pidx(511)+1 = 546)

__device__ __forceinline__ float2 f2(float x, float y){ return make_float2(x, y); }
__device__ __forceinline__ float2 cadd(float2 a, float2 b){ return f2(a.x+b.x, a.y+b.y); }
__device__ __forceinline__ float2 csub(float2 a, float2 b){ return f2(a.x-b.x, a.y-b.y); }
__device__ __forceinline__ float2 cmul(float2 a, float2 b){
    return f2(a.x*b.x - a.y*b.y, a.x*b.y + a.y*b.x);
}
// LDS padding: spreads banks across all three radix-8 stage access patterns
__device__ __forceinline__ int pidx(int p){ return p + (p>>4) + (p>>7); }
// intra-wave fence: LDS ops of one wave execute in program order (validated R2)
#define WFENCE() __builtin_amdgcn_wave_barrier()

// 8-point DFT (symmetric matrix). SGN=-1: forward, SGN=+1: inverse kernel (no 1/N)
template<int SGN>
__device__ __forceinline__ void fft8(float2 a[8]){
    const float r = 0.7071067811865476f;
    const float S = (float)SGN;
    float2 u0 = cadd(a[0], a[4]), u1 = cadd(a[1], a[5]);
    float2 u2 = cadd(a[2], a[6]), u3 = cadd(a[3], a[7]);
    float2 v0 = csub(a[0], a[4]), v1 = csub(a[1], a[5]);
    float2 v2 = csub(a[2], a[6]), v3 = csub(a[3], a[7]);
    v1 = cmul(v1, f2(r, S*r));
    v2 = cmul(v2, f2(0.f, S));
    v3 = cmul(v3, f2(-r, S*r));
    float2 p0 = cadd(u0, u2), p1 = cadd(u1, u3);
    float2 q0 = csub(u0, u2), q1 = cmul(csub(u1, u3), f2(0.f, S));
    a[0] = cadd(p0, p1); a[4] = csub(p0, p1);
    a[2] = cadd(q0, q1); a[6] = csub(q0, q1);
    p0 = cadd(v0, v2); p1 = cadd(v1, v3);
    q0 = csub(v0, v2); q1 = cmul(csub(v1, v3), f2(0.f, S));
    a[1] = cadd(p0, p1); a[5] = csub(p0, p1);
    a[3] = cadd(q0, q1); a[7] = csub(q0, q1);
}

__device__ __forceinline__ float2 twdp(int idx, float inv){
    float ang = 6.283185307179586f * (inv * (float)idx);
    float s, c;
    __sincosf(ang, &s, &c);
    return f2(c, s);
}

// DIF radix-8^3, inline chain twiddles, pidx-padded scratch.
// In: v[q] = x[lane+64q] (natural). Out (REGS): v[k2] = X[64k2+8(lane&7)+(lane>>3)].
template<int SGN>
__device__ void fft512_dif_i(float2 v[8], float2* buf, int lane){
    fft8<SGN>(v);
    {
        float2 w1 = twdp(lane, 1.f/512.f);
        if (SGN < 0) w1.y = -w1.y;
        float2 w  = f2(1.f, 0.f);
        #pragma unroll
        for (int r = 0; r < 8; ++r){
            buf[pidx(r*64 + lane)] = cmul(v[r], w);
            w = cmul(w, w1);
        }
    }
    WFENCE();
    int rb = (lane >> 3) * 64, t2 = lane & 7;
    float2 y[8];
    #pragma unroll
    for (int q = 0; q < 8; ++q) y[q] = buf[pidx(rb + t2 + 8*q)];
    fft8<SGN>(y);
    WFENCE();
    {
        float2 w2 = twdp(t2, 1.f/64.f);
        if (SGN < 0) w2.y = -w2.y;
        float2 w  = f2(1.f, 0.f);
        #pragma unroll
        for (int r = 0; r < 8; ++r){
            buf[pidx(rb + r*8 + t2)] = cmul(y[r], w);
            w = cmul(w, w2);
        }
    }
    WFENCE();
    int base = rb + t2*8;
    #pragma unroll
    for (int q = 0; q < 8; ++q) v[q] = buf[pidx(base + q)];
    fft8<SGN>(v);
}

// DIT (transposed DIF), inline chains, pidx scratch. In (REGS): tau slots. Out: natural.
template<int SGN>
__device__ void fft512_dit_i(float2 v[8], float2* buf, int lane){
    int rb = (lane >> 3) * 64, t2 = lane & 7;
    fft8<SGN>(v);
    int base = rb + t2*8;
    #pragma unroll
    for (int q = 0; q < 8; ++q) buf[pidx(base + q)] = v[q];
    WFENCE();
    float2 y[8];
    #pragma unroll
    for (int r = 0; r < 8; ++r) y[r] = buf[pidx(rb + r*8 + t2)];
    {
        float2 w2 = twdp(t2, 1.f/64.f);
        if (SGN < 0) w2.y = -w2.y;
        float2 w  = f2(1.f, 0.f);
        #pragma unroll
        for (int r = 0; r < 8; ++r){
            y[r] = cmul(y[r], w);
            w = cmul(w, w2);
        }
    }
    fft8<SGN>(y);
    WFENCE();
    #pragma unroll
    for (int q = 0; q < 8; ++q) buf[pidx(rb + t2 + 8*q)] = y[q];
    WFENCE();
    #pragma unroll
    for (int r = 0; r < 8; ++r) v[r] = buf[pidx(r*64 + lane)];
    {
        float2 w1 = twdp(lane, 1.f/512.f);
        if (SGN < 0) w1.y = -w1.y;
        float2 w  = f2(1.f, 0.f);
        #pragma unroll
        for (int r = 0; r < 8; ++r){
            v[r] = cmul(v[r], w);
            w = cmul(w, w1);
        }
    }
    fft8<SGN>(v);
}

// K1: temp[kj] = row-IFFT( x_hat * psi_hat[kj] ), fp16 tau slots, row-major;
// also emits psi2 = |psi|^2 fp16 (natural order).
__global__ __launch_bounds__(256, 6)
void k_mulrow(const float2* __restrict__ xh, const float* __restrict__ pr,
              const float* __restrict__ pi, __half2* __restrict__ temp,
              __half* __restrict__ psi2h){
    __shared__ float2 lds[4][548];
    int wave = threadIdx.x >> 6, lane = threadIdx.x & 63;
    int img  = blockIdx.x >> 7;
    int row  = ((blockIdx.x & 127) << 2) | wave;
    size_t boff = (size_t)img * NNe + (size_t)row * Nn;
    const float2* xr = xh + (size_t)row * Nn;
    float2 v[8];
    #pragma unroll
    for (int q = 0; q < 8; ++q){
        int x = lane + 64*q;
        float2 xv = xr[x];
        float2 pv = f2(pr[boff + x], pi[boff + x]);
        psi2h[boff + x] = __float2half_rn(pv.x*pv.x + pv.y*pv.y);
        v[q] = cmul(xv, pv);
    }
    fft512_dif_i<1>(v, lds[wave], lane);
    __half2* outp = temp + boff;
    #pragma unroll
    for (int q = 0; q < 8; ++q) outp[64*q + lane] = __floats2half2_rn(v[q].x, v[q].y);
}

// K2 (fused, R12-proven best): col-IFFT + modulus + packed-real col-FFT.
// 16-column tiles (full 64-B read sectors); 8 waves, 2 cols/wave via Hermitian pack.
__global__ __launch_bounds__(512, 2)
void k_colfused(__half2* __restrict__ temp){
    __shared__ __half2 st[16][521];
    __shared__ float2 fbuf[8][CST];
    int img = blockIdx.x >> 5;
    int x0  = (blockIdx.x & 31) << 4;
    __half2* src = temp + (size_t)img * NNe + x0;
    for (int i = threadIdx.x; i < 2048; i += 512){
        int row = i >> 2, c4 = (i & 3) << 2;
        uint4 u = *(const uint4*)&src[(size_t)row * Nn + c4];
        st[c4+0][row] = *(__half2*)&u.x;
        st[c4+1][row] = *(__half2*)&u.y;
        st[c4+2][row] = *(__half2*)&u.z;
        st[c4+3][row] = *(__half2*)&u.w;
    }
    __syncthreads();
    int wave = threadIdx.x >> 6, lane = threadIdx.x & 63;
    const float sc = 3.814697265625e-06f;   // 1/NN (ifft2 normalization)
    float2* buf = fbuf[wave];
    int c0 = 2*wave, c1 = c0 + 1;
    float2 a[8], b[8];
    #pragma unroll
    for (int q = 0; q < 8; ++q) a[q] = __half22float2(st[c0][lane + 64*q]);
    fft512_dif_i<1>(a, buf, lane);          // col IFFT c0 -> tau regs
    WFENCE();
    #pragma unroll
    for (int q = 0; q < 8; ++q) b[q] = __half22float2(st[c1][lane + 64*q]);
    fft512_dif_i<1>(b, buf, lane);          // col IFFT c1 -> tau regs
    // modulus (pointwise, order-free) and pack: z = m0 + i*m1
    float2 z[8];
    #pragma unroll
    for (int q = 0; q < 8; ++q){
        float r0 = a[q].x*sc, i0 = a[q].y*sc;
        float r1 = b[q].x*sc, i1 = b[q].y*sc;
        z[q] = f2(sqrtf(r0*r0 + i0*i0 + 1e-8f), sqrtf(r1*r1 + i1*i1 + 1e-8f));
    }
    WFENCE();
    fft512_dit_i<-1>(z, buf, lane);         // one FFT for two real columns
    // Hermitian unpack: M0=(Z[k]+conj(Z[-k]))/2, M1=-i(Z[k]-conj(Z[-k]))/2
    #pragma unroll
    for (int q = 0; q < 8; ++q) buf[pidx(lane + 64*q)] = z[q];
    WFENCE();
    #pragma unroll
    for (int q = 0; q < 8; ++q){
        int k = lane + 64*q;
        float2 zr = buf[pidx((512 - k) & 511)];
        float2 zv = z[q];
        st[c0][k] = __floats2half2_rn(0.5f*(zv.x + zr.x), 0.5f*(zv.y - zr.y));
        st[c1][k] = __floats2half2_rn(0.5f*(zv.y + zr.y), 0.5f*(zr.x - zv.x));
    }
    __syncthreads();
    for (int i = threadIdx.x; i < 2048; i += 512){
        int row = i >> 2, c4 = (i & 3) << 2;
        uint4 u;
        *(__half2*)&u.x = st[c4+0][row];
        *(__half2*)&u.y = st[c4+1][row];
        *(__half2*)&u.z = st[c4+2][row];
        *(__half2*)&u.w = st[c4+3][row];
        *(uint4*)&src[(size_t)row * Nn + c4] = u;
    }
}

// K3: row FFT + |.|^2 -> power fp16 (scaled 2^-8).
__global__ __launch_bounds__(256, 6)
void k_rowpow(const __half2* __restrict__ temp, __half* __restrict__ powerh){
    __shared__ float2 lds[4][548];
    int wave = threadIdx.x >> 6, lane = threadIdx.x & 63;
    int img  = blockIdx.x >> 7;
    int row  = ((blockIdx.x & 127) << 2) | wave;
    const __half2* src = temp + (size_t)img * NNe + (size_t)row * Nn;
    float2 v[8];
    #pragma unroll
    for (int q = 0; q < 8; ++q) v[q] = __half22float2(src[64*q + lane]);
    fft512_dit_i<-1>(v, lds[wave], lane);
    __half* dst = powerh + (size_t)img * NNe + (size_t)row * Nn;
    #pragma unroll
    for (int q = 0; q < 8; ++q)
        dst[lane + 64*q] = __float2half_rn((v[q].x*v[q].x + v[q].y*v[q].y) * 0.00390625f);
}

// K5: C[48][49] = power[48][NN] x {psi2, phi2}[NN][49]. One block (4 waves) per
// 256-n slice; BLOCK-SHARED tiles (staged once, used by all 4 waves); wave w owns
// output cols [13w, 13w+13). acc[6][2] regs. Also accumulates s0 partial (wave 0).
__global__ __launch_bounds__(256, 5)
void k_gemm(const __half* __restrict__ powerh, const __half* __restrict__ psi2h,
            const float* __restrict__ phr, const float* __restrict__ phii,
            const float2* __restrict__ xh, float* __restrict__ partC,
            float* __restrict__ partS0){
    __shared__ __align__(16) float P[48][68];
    __shared__ __align__(16) float W[56][68];
    int tid = threadIdx.x;
    int wave = tid >> 6, lane = tid & 63;
    int lm = lane >> 3, lw = lane & 7;
    float acc[6][2] = {};
    float s0acc = 0.f;
    // zero W pad rows once (rows 49..55)
    if (tid < 224){
        int r = 49 + (tid >> 5), c = (tid & 31);
        W[r][c] = 0.f; W[r][32 + c] = 0.f;
        if (c < 4) W[r][64 + c] = 0.f;
    }
    int n0 = blockIdx.x * 256;
    for (int st = 0; st < 4; ++st){
        int nb = n0 + st*64;
        __syncthreads();
        #pragma unroll
        for (int rr = 0; rr < 3; ++rr){
            int row = rr*16 + (tid >> 4);
            int c4  = (tid & 15) * 4;
            size_t off = (size_t)row*NNe + nb + c4;
            const __half2* p2 = (const __half2*)&powerh[off];
            float2 f0 = __half22float2(p2[0]);
            float2 f1 = __half22float2(p2[1]);
            *(float4*)&P[row][c4] = make_float4(f0.x, f0.y, f1.x, f1.y);
        }
        #pragma unroll
        for (int rr = 0; rr < 3; ++rr){
            int row = rr*16 + (tid >> 4);
            int c4  = (tid & 15) * 4;
            size_t off = (size_t)row*NNe + nb + c4;
            const __half2* p2 = (const __half2*)&psi2h[off];
            float2 f0 = __half22float2(p2[0]);
            float2 f1 = __half22float2(p2[1]);
            *(float4*)&W[row][c4] = make_float4(f0.x, f0.y, f1.x, f1.y);
        }
        if (tid < 16){
            int c4 = tid * 4;
            float4 a = *(const float4*)&phr[nb + c4];
            float4 b = *(const float4*)&phii[nb + c4];
            float4 w4;
            w4.x = a.x*a.x + b.x*b.x; w4.y = a.y*a.y + b.y*b.y;
            w4.z = a.z*a.z + b.z*b.z; w4.w = a.w*a.w + b.w*b.w;
            *(float4*)&W[48][c4] = w4;
        }
        __syncthreads();
        if (wave == 0){  // s0 partial: |x_hat[nb+lane]|^2 * phi2[nb+lane]
            float2 xv = xh[nb + lane];
            s0acc = fmaf(xv.x*xv.x + xv.y*xv.y, W[48][lane], s0acc);
        }
        int cb = wave * 13;      // this wave's column base
        #pragma unroll 2
        for (int nn = 0; nn < 64; nn += 4){
            float4 pa[6], wb[2];
            #pragma unroll
            for (int i = 0; i < 6; ++i) pa[i] = *(const float4*)&P[lm + 8*i][nn];
            #pragma unroll
            for (int j = 0; j < 2; ++j) wb[j] = *(const float4*)&W[cb + lw + 8*j][nn];
            #pragma unroll
            for (int i = 0; i < 6; ++i)
                #pragma unroll
                for (int j = 0; j < 2; ++j){
                    float s = acc[i][j];
                    s = fmaf(pa[i].x, wb[j].x, s);
                    s = fmaf(pa[i].y, wb[j].y, s);
                    s = fmaf(pa[i].z, wb[j].z, s);
                    s = fmaf(pa[i].w, wb[j].w, s);
                    acc[i][j] = s;
                }
        }
    }
    if (wave == 0){
        #pragma unroll
        for (int o = 32; o > 0; o >>= 1) s0acc += __shfl_down(s0acc, o, 64);
        if (lane == 0) partS0[blockIdx.x] = s0acc;
    }
    float* outp = partC + (size_t)blockIdx.x * 2400;
    int cb = wave * 13;
    #pragma unroll
    for (int i = 0; i < 6; ++i)
        #pragma unroll
        for (int j = 0; j < 2; ++j){
            int cr = lw + 8*j;           // 0..15, valid < 13
            int wc = cb + cr;
            int m  = lm + 8*i;
            if (cr < 13 && wc < 49) outp[m*50 + wc] = acc[i][j];
        }
}

// reduce 1024 partial C slices -> 16 slices
__global__ __launch_bounds__(256)
void k_redc1(const float* __restrict__ partC, float* __restrict__ partC2){
    __shared__ float red[4][64];
    int es = threadIdx.x & 63, wave = threadIdx.x >> 6;
    int e = blockIdx.x*64 + es;
    int b0 = blockIdx.y*64 + wave*16;
    float s = 0.f;
    if (e < 2400){
        #pragma unroll
        for (int u = 0; u < 16; ++u) s += partC[(size_t)(b0+u)*2400 + e];
    }
    red[wave][es] = s;
    __syncthreads();
    if (wave == 0 && e < 2400)
        partC2[(size_t)blockIdx.y*2400 + e] = red[0][es]+red[1][es]+red[2][es]+red[3][es];
}

// final: fold 16 slices -> CF (LDS), s0 (1024 partials), assemble 1009-elem output
__global__ __launch_bounds__(256)
void k_final(const float* __restrict__ partC2, const float* __restrict__ partS0,
             float* __restrict__ outp, float SC0, float SCC){
    __shared__ float CFs[2400];
    __shared__ float ssum[4];
    int tid = threadIdx.x, wave = tid >> 6, lane = tid & 63;
    for (int e = tid; e < 2400; e += 256){
        float s = 0.f;
        #pragma unroll
        for (int u = 0; u < 16; ++u) s += partC2[(size_t)u*2400 + e];
        CFs[e] = SCC * s;
    }
    float a = 0.f;
    #pragma unroll
    for (int u = 0; u < 4; ++u) a += partS0[tid + 256*u];
    #pragma unroll
    for (int o = 32; o > 0; o >>= 1) a += __shfl_down(a, o, 64);
    if (lane == 0) ssum[wave] = a;
    __syncthreads();
    if (tid == 0) outp[0] = SC0 * (ssum[0]+ssum[1]+ssum[2]+ssum[3]);
    int off = 1;
    for (int i = 0; i < 6; ++i){
        if (tid < 8) outp[off + tid] = CFs[(tid*6 + i)*50 + 48];   // a[:, i]
        off += 8;
        if (i < 5){
            int nj = 5 - i, cnt = 64 * nj;
            for (int p = tid; p < cnt; p += 256){
                int j2 = p % nj;
                int km = p / nj;
                int m = km & 7, k = km >> 3;
                outp[off + p] = CFs[(k*6 + i)*50 + m*6 + (i + 1 + j2)];
            }
            off += cnt;
        }
    }
}

extern "C" void kernel_launch(void* const* d_in, const int* in_sizes, int n_in,
                              void* d_out, int out_size, void* d_ws, size_t ws_size,
                              hipStream_t stream){
    (void)in_sizes; (void)n_in; (void)out_size; (void)ws_size;
    const float2* xh  = (const float2*)d_in[0];
    const float*  phr = (const float*)d_in[1];
    const float*  phi_= (const float*)d_in[2];
    const float*  psr = (const float*)d_in[3];
    const float*  psi_= (const float*)d_in[4];
    float* outp = (float*)d_out;
    float* ws   = (float*)d_ws;

    // ws layout (f32 units): power(half)[24NN] | partC[1024*2400] | partC2[16*2400] |
    //                        s0[1024] | temp(half2)[48NN] | psi2(half)[24NN]
    size_t o_power = 0;
    size_t o_partC = o_power + (size_t)24 * NNe;
    size_t o_pC2   = o_partC + (size_t)1024 * 2400;
    size_t o_s0    = o_pC2 + (size_t)16 * 2400;
    size_t o_temp  = o_s0 + 1024;
    size_t o_psi2  = o_temp + (size_t)48 * NNe;
    __half*  powerh= (__half*)(ws + o_power);
    float*   partC = ws + o_partC;
    float*   partC2= ws + o_pC2;
    float*   ps0   = ws + o_s0;
    __half2* temp  = (__half2*)(ws + o_temp);
    __half*  psi2h = (__half*)(ws + o_psi2);

    const double INVd = 1.0 / (4.0 * 3.14159265358979323846 * 3.14159265358979323846);
    const float SC0 = (float)(INVd / (double)NNe);          // INV / NN (s0 path)
    const float SCC = (float)(INVd / (double)NNe * 256.0);  // + 2^8 power descale

    k_mulrow<<<dim3(48*128), dim3(256), 0, stream>>>(xh, psr, psi_, temp, psi2h);
    k_colfused<<<dim3(48*32), dim3(512), 0, stream>>>(temp);
    k_rowpow<<<dim3(48*128), dim3(256), 0, stream>>>(temp, powerh);
    k_gemm<<<dim3(1024), dim3(256), 0, stream>>>(powerh, psi2h, phr, phi_, xh, partC, ps0);
    k_redc1<<<dim3(38, 16), dim3(256), 0, stream>>>(partC, partC2);
    k_final<<<dim3(1), dim3(256), 0, stream>>>(partC2, ps0, outp, SC0, SCC);
}